// Round 3
// baseline (1622.636 us; speedup 1.0000x reference)
//
#include <hip/hip_runtime.h>

#define D 256
#define NE 8192
#define NZ 16384
#define BM 128
#define BN 128
#define BK 32
#define LDA (BM + 4)          // padded k-major stride
#define NSPLIT 4
#define SPLIT_N (NE / NSPLIT) // 2048

// workspace layout (bytes)
#define WS_SUMS   0                          // double[4]: 0=sum_emb2 1=sum_diff2 2=sum_maxmin
#define WS_ZSQ    64                         // float[NZ]  np-pairwise ||z_i||^2
#define WS_ESQ    (WS_ZSQ + NZ * 4)          // float[NE]  np-pairwise ||e_j||^2
#define WS_IDX    (WS_ESQ + NE * 4)          // int[NZ]
#define WS_PS1    (WS_IDX + NZ * 4)          // float[NZ*NSPLIT]
#define WS_PIX    (WS_PS1 + NZ * NSPLIT * 4) // int[NZ*NSPLIT]
#define WS_PMAX   (WS_PIX + NZ * NSPLIT * 4) // float[NE*NSPLIT]
#define WS_PMIN   (WS_PMAX + NE * NSPLIT * 4)

__device__ __forceinline__ float waveReduceSumF(float v) {
    v += __shfl_down(v, 32);
    v += __shfl_down(v, 16);
    v += __shfl_down(v, 8);
    v += __shfl_down(v, 4);
    v += __shfl_down(v, 2);
    v += __shfl_down(v, 1);
    return v;
}

__device__ __forceinline__ double waveReduceSumD(double v) {
    v += __shfl_down(v, 32);
    v += __shfl_down(v, 16);
    v += __shfl_down(v, 8);
    v += __shfl_down(v, 4);
    v += __shfl_down(v, 2);
    v += __shfl_down(v, 1);
    return v;
}

__global__ void k_init(double* sums) {
    sums[0] = 0.0; sums[1] = 0.0; sums[2] = 0.0; sums[3] = 0.0;
}

// np.sum(x*x, axis=1) replicated bit-exactly (numpy pairwise summation, n=256:
// two 128-blocks, each with 8 stride-8 accumulators, then pairwise combine).
// __fmul_rn/__fadd_rn prevent FMA contraction (numpy rounds x*x first).
__global__ __launch_bounds__(256) void k_rowsq(const float* __restrict__ src,
                                               float* __restrict__ rsq,
                                               double* __restrict__ sums) {
    const int row = blockIdx.x * 256 + threadIdx.x;
    const float* p = src + (size_t)row * D;
    float h[2];
#pragma unroll
    for (int half = 0; half < 2; ++half) {
        const float* q = p + half * 128;
        float4 a0 = *(const float4*)&q[0];
        float4 a1 = *(const float4*)&q[4];
        float r0 = __fmul_rn(a0.x, a0.x);
        float r1 = __fmul_rn(a0.y, a0.y);
        float r2 = __fmul_rn(a0.z, a0.z);
        float r3 = __fmul_rn(a0.w, a0.w);
        float r4 = __fmul_rn(a1.x, a1.x);
        float r5 = __fmul_rn(a1.y, a1.y);
        float r6 = __fmul_rn(a1.z, a1.z);
        float r7 = __fmul_rn(a1.w, a1.w);
#pragma unroll
        for (int i = 8; i < 128; i += 8) {
            const float4 b0 = *(const float4*)&q[i];
            const float4 b1 = *(const float4*)&q[i + 4];
            r0 = __fadd_rn(r0, __fmul_rn(b0.x, b0.x));
            r1 = __fadd_rn(r1, __fmul_rn(b0.y, b0.y));
            r2 = __fadd_rn(r2, __fmul_rn(b0.z, b0.z));
            r3 = __fadd_rn(r3, __fmul_rn(b0.w, b0.w));
            r4 = __fadd_rn(r4, __fmul_rn(b1.x, b1.x));
            r5 = __fadd_rn(r5, __fmul_rn(b1.y, b1.y));
            r6 = __fadd_rn(r6, __fmul_rn(b1.z, b1.z));
            r7 = __fadd_rn(r7, __fmul_rn(b1.w, b1.w));
        }
        const float t01 = __fadd_rn(r0, r1);
        const float t23 = __fadd_rn(r2, r3);
        const float t45 = __fadd_rn(r4, r5);
        const float t67 = __fadd_rn(r6, r7);
        h[half] = __fadd_rn(__fadd_rn(t01, t23), __fadd_rn(t45, t67));
    }
    const float tot = __fadd_rn(h[0], h[1]);
    rsq[row] = tot;
    if (sums != nullptr) {
        double s = waveReduceSumD((double)tot);
        if ((threadIdx.x & 63) == 0) atomicAdd(&sums[0], s);
    }
}

// ---- argmin over codes, replicating np fp32: d = fl(fl(zsq+esq) - 2*dot) ----
// dot accumulated serial-ascending-k single-accumulator FMA (= OpenBLAS sgemm microkernel)
__global__ __launch_bounds__(256) void k_argmin(const float* __restrict__ z,
                                                const float* __restrict__ emb,
                                                const float* __restrict__ zsq,
                                                const float* __restrict__ esq,
                                                float* __restrict__ ps1,
                                                int* __restrict__ pidx) {
    __shared__ float As[BK * LDA];
    __shared__ float Bs[BK * LDA];
    __shared__ float Sq[BN];

    const int t = threadIdx.x;
    const int row0  = blockIdx.x * BM;
    const int sp    = blockIdx.y;
    const int cbase = sp * SPLIT_N;

    const int tr = t >> 4;   // rows tr*8 .. tr*8+7
    const int tc = t & 15;   // cols tc*4..+3 and 64+tc*4..+3
    const int sr  = t >> 3;
    const int skq = t & 7;

    float zqr[8];
#pragma unroll
    for (int i = 0; i < 8; ++i) zqr[i] = zsq[row0 + tr * 8 + i];

    float best[8];
    int   bidx[8];
#pragma unroll
    for (int i = 0; i < 8; ++i) { best[i] = 3.4e38f; bidx[i] = 0; }

    for (int ch = 0; ch < SPLIT_N; ch += BN) {
        const int c0 = cbase + ch;
        if (t < BN) Sq[t] = esq[c0 + t];

        float acc[8][8];
#pragma unroll
        for (int i = 0; i < 8; ++i)
#pragma unroll
            for (int j = 0; j < 8; ++j) acc[i][j] = 0.f;

        for (int kb = 0; kb < D; kb += BK) {
            __syncthreads();
#pragma unroll
            for (int q = 0; q < 4; ++q) {
                const int r = sr + 32 * q;
                const float4 av = *(const float4*)&z[(size_t)(row0 + r) * D + kb + 4 * skq];
                const float4 bv = *(const float4*)&emb[(size_t)(c0 + r) * D + kb + 4 * skq];
                As[(4 * skq + 0) * LDA + r] = av.x;
                As[(4 * skq + 1) * LDA + r] = av.y;
                As[(4 * skq + 2) * LDA + r] = av.z;
                As[(4 * skq + 3) * LDA + r] = av.w;
                Bs[(4 * skq + 0) * LDA + r] = bv.x;
                Bs[(4 * skq + 1) * LDA + r] = bv.y;
                Bs[(4 * skq + 2) * LDA + r] = bv.z;
                Bs[(4 * skq + 3) * LDA + r] = bv.w;
            }
            __syncthreads();
#pragma unroll
            for (int k = 0; k < BK; ++k) {
                const float4 a0 = *(const float4*)&As[k * LDA + tr * 8];
                const float4 a1 = *(const float4*)&As[k * LDA + tr * 8 + 4];
                const float4 b0 = *(const float4*)&Bs[k * LDA + tc * 4];
                const float4 b1 = *(const float4*)&Bs[k * LDA + 64 + tc * 4];
                const float a[8] = {a0.x, a0.y, a0.z, a0.w, a1.x, a1.y, a1.z, a1.w};
                const float b[8] = {b0.x, b0.y, b0.z, b0.w, b1.x, b1.y, b1.z, b1.w};
#pragma unroll
                for (int i = 0; i < 8; ++i)
#pragma unroll
                    for (int j = 0; j < 8; ++j)
                        acc[i][j] = fmaf(a[i], b[j], acc[i][j]);
            }
        }
        // epilogue: np-fp32 score + running argmin (cols ascending; strict < = first min)
#pragma unroll
        for (int jj = 0; jj < 8; ++jj) {
            const int cloc = (jj < 4) ? (tc * 4 + jj) : (64 + tc * 4 + (jj - 4));
            const float sq = Sq[cloc];
            const int gcol = c0 + cloc;
#pragma unroll
            for (int i = 0; i < 8; ++i) {
                const float t1 = __fadd_rn(zqr[i], sq);
                const float s  = fmaf(-2.f, acc[i][jj], t1);
                if (s < best[i]) { best[i] = s; bidx[i] = gcol; }
            }
        }
        __syncthreads();
    }

    // cross-thread reduction per row (reuse LDS); tie -> lowest index (np.argmin)
    float* Rs = As;
    int*   Ri = (int*)Bs;
#pragma unroll
    for (int i = 0; i < 8; ++i) {
        Rs[(tr * 8 + i) * 16 + tc] = best[i];
        Ri[(tr * 8 + i) * 16 + tc] = bidx[i];
    }
    __syncthreads();
    if (t < BM) {
        float bs = Rs[t * 16];
        int   bi = Ri[t * 16];
#pragma unroll
        for (int c = 1; c < 16; ++c) {
            const float s = Rs[t * 16 + c];
            const int  ii = Ri[t * 16 + c];
            if (s < bs || (s == bs && ii < bi)) { bs = s; bi = ii; }
        }
        ps1[(size_t)(row0 + t) * NSPLIT + sp] = bs;
        pidx[(size_t)(row0 + t) * NSPLIT + sp] = bi;
    }
}

__global__ __launch_bounds__(256) void k_merge(const float* __restrict__ ps,
                                               const int* __restrict__ pi,
                                               int* __restrict__ idxbuf,
                                               float* __restrict__ outidx) {
    const int n = blockIdx.x * 256 + threadIdx.x;
    float bs = ps[n * NSPLIT];
    int   bi = pi[n * NSPLIT];
#pragma unroll
    for (int s2 = 1; s2 < NSPLIT; ++s2) {
        const float v = ps[n * NSPLIT + s2];
        const int  ii = pi[n * NSPLIT + s2];
        if (v < bs || (v == bs && ii < bi)) { bs = v; bi = ii; }
    }
    idxbuf[n] = bi;
    outidx[n] = (float)bi;
}

// gather z_q into out + accumulate sum((z_q - z)^2)
__global__ __launch_bounds__(256) void k_gather(const float* __restrict__ z,
                                                const float* __restrict__ emb,
                                                const int* __restrict__ idxbuf,
                                                float* __restrict__ out,
                                                double* __restrict__ sums) {
    const int row  = blockIdx.x * 4 + (threadIdx.x >> 6);
    const int lane = threadIdx.x & 63;
    const int idx  = idxbuf[row];
    const float4 e4 = *(const float4*)&emb[(size_t)idx * D + lane * 4];
    const float4 z4 = *(const float4*)&z[(size_t)row * D + lane * 4];
    *(float4*)&out[(size_t)row * D + lane * 4] = e4;
    const float dx = e4.x - z4.x, dy = e4.y - z4.y;
    const float dzv = e4.z - z4.z, dw = e4.w - z4.w;
    float s = dx * dx + dy * dy + dzv * dzv + dw * dw;
    s = waveReduceSumF(s);
    if (lane == 0) atomicAdd(&sums[1], (double)s);
}

// ---- pairwise cdist row max / min (incl. diagonal zero) ----
__global__ __launch_bounds__(256) void k_pairwise(const float* __restrict__ emb,
                                                  const float* __restrict__ esq,
                                                  float* __restrict__ pmax,
                                                  float* __restrict__ pmin) {
    __shared__ float As[BK * LDA];
    __shared__ float Bs[BK * LDA];
    __shared__ float Sq[BN];

    const int t = threadIdx.x;
    const int row0  = blockIdx.x * BM;
    const int sp    = blockIdx.y;
    const int cbase = sp * SPLIT_N;

    const int tr = t >> 4;
    const int tc = t & 15;
    const int sr  = t >> 3;
    const int skq = t & 7;

    float rsq[8];
#pragma unroll
    for (int i = 0; i < 8; ++i) rsq[i] = esq[row0 + tr * 8 + i];

    float rmax[8], rmin[8];
#pragma unroll
    for (int i = 0; i < 8; ++i) { rmax[i] = 0.f; rmin[i] = 3.4e38f; }

    for (int ch = 0; ch < SPLIT_N; ch += BN) {
        const int c0 = cbase + ch;
        if (t < BN) Sq[t] = esq[c0 + t];

        float acc[8][8];
#pragma unroll
        for (int i = 0; i < 8; ++i)
#pragma unroll
            for (int j = 0; j < 8; ++j) acc[i][j] = 0.f;

        for (int kb = 0; kb < D; kb += BK) {
            __syncthreads();
#pragma unroll
            for (int q = 0; q < 4; ++q) {
                const int r = sr + 32 * q;
                const float4 av = *(const float4*)&emb[(size_t)(row0 + r) * D + kb + 4 * skq];
                const float4 bv = *(const float4*)&emb[(size_t)(c0 + r) * D + kb + 4 * skq];
                As[(4 * skq + 0) * LDA + r] = av.x;
                As[(4 * skq + 1) * LDA + r] = av.y;
                As[(4 * skq + 2) * LDA + r] = av.z;
                As[(4 * skq + 3) * LDA + r] = av.w;
                Bs[(4 * skq + 0) * LDA + r] = bv.x;
                Bs[(4 * skq + 1) * LDA + r] = bv.y;
                Bs[(4 * skq + 2) * LDA + r] = bv.z;
                Bs[(4 * skq + 3) * LDA + r] = bv.w;
            }
            __syncthreads();
#pragma unroll
            for (int k = 0; k < BK; ++k) {
                const float4 a0 = *(const float4*)&As[k * LDA + tr * 8];
                const float4 a1 = *(const float4*)&As[k * LDA + tr * 8 + 4];
                const float4 b0 = *(const float4*)&Bs[k * LDA + tc * 4];
                const float4 b1 = *(const float4*)&Bs[k * LDA + 64 + tc * 4];
                const float a[8] = {a0.x, a0.y, a0.z, a0.w, a1.x, a1.y, a1.z, a1.w};
                const float b[8] = {b0.x, b0.y, b0.z, b0.w, b1.x, b1.y, b1.z, b1.w};
#pragma unroll
                for (int i = 0; i < 8; ++i)
#pragma unroll
                    for (int j = 0; j < 8; ++j)
                        acc[i][j] = fmaf(a[i], b[j], acc[i][j]);
            }
        }
#pragma unroll
        for (int jj = 0; jj < 8; ++jj) {
            const int cloc = (jj < 4) ? (tc * 4 + jj) : (64 + tc * 4 + (jj - 4));
            const float sq = Sq[cloc];
#pragma unroll
            for (int i = 0; i < 8; ++i) {
                const float t1 = __fadd_rn(rsq[i], sq);
                const float d2 = fmaf(-2.f, acc[i][jj], t1);
                const float dd = (d2 > 0.f) ? sqrtf(d2) : 0.f;
                rmax[i] = fmaxf(rmax[i], dd);
                rmin[i] = fminf(rmin[i], dd);
            }
        }
        __syncthreads();
    }

    float* Rmx = As;
    float* Rmn = Bs;
#pragma unroll
    for (int i = 0; i < 8; ++i) {
        Rmx[(tr * 8 + i) * 16 + tc] = rmax[i];
        Rmn[(tr * 8 + i) * 16 + tc] = rmin[i];
    }
    __syncthreads();
    if (t < BM) {
        float mx = Rmx[t * 16];
        float mn = Rmn[t * 16];
#pragma unroll
        for (int c = 1; c < 16; ++c) {
            mx = fmaxf(mx, Rmx[t * 16 + c]);
            mn = fminf(mn, Rmn[t * 16 + c]);
        }
        pmax[(size_t)(row0 + t) * NSPLIT + sp] = mx;
        pmin[(size_t)(row0 + t) * NSPLIT + sp] = mn;
    }
}

__global__ __launch_bounds__(256) void k_mm_sum(const float* __restrict__ pmax,
                                                const float* __restrict__ pmin,
                                                double* __restrict__ sums) {
    const int n = blockIdx.x * 256 + threadIdx.x;
    float mx = pmax[n * NSPLIT];
    float mn = pmin[n * NSPLIT];
#pragma unroll
    for (int s2 = 1; s2 < NSPLIT; ++s2) {
        mx = fmaxf(mx, pmax[n * NSPLIT + s2]);
        mn = fminf(mn, pmin[n * NSPLIT + s2]);
    }
    float v = mx - mn;
    v = waveReduceSumF(v);
    __shared__ float part[4];
    if ((threadIdx.x & 63) == 0) part[threadIdx.x >> 6] = v;
    __syncthreads();
    if (threadIdx.x == 0)
        atomicAdd(&sums[2], (double)(part[0] + part[1] + part[2] + part[3]));
}

__global__ void k_final(const double* __restrict__ sums, float* __restrict__ out) {
    const double loss = 1.25 * (sums[1] / (double)((size_t)NZ * D));       // (1+beta)*mean(diff^2)
    const double qq   = 0.1 * (sums[2] / (double)NE) + 0.1 * sums[0];      // uniform + reg
    out[(size_t)NZ * D + NZ]     = (float)loss;
    out[(size_t)NZ * D + NZ + 1] = (float)qq;
}

extern "C" void kernel_launch(void* const* d_in, const int* in_sizes, int n_in,
                              void* d_out, int out_size, void* d_ws, size_t ws_size,
                              hipStream_t stream) {
    const float* z   = (const float*)d_in[0];
    const float* emb = (const float*)d_in[1];
    float* out = (float*)d_out;
    char*  ws  = (char*)d_ws;

    double* sums = (double*)(ws + WS_SUMS);
    float*  zsq  = (float*)(ws + WS_ZSQ);
    float*  esq  = (float*)(ws + WS_ESQ);
    int*    idxb = (int*)(ws + WS_IDX);
    float*  ps1  = (float*)(ws + WS_PS1);
    int*    pix  = (int*)(ws + WS_PIX);
    float*  pmax = (float*)(ws + WS_PMAX);
    float*  pmin = (float*)(ws + WS_PMIN);

    hipLaunchKernelGGL(k_init, dim3(1), dim3(1), 0, stream, sums);
    hipLaunchKernelGGL(k_rowsq, dim3(NZ / 256), dim3(256), 0, stream, z, zsq, (double*)nullptr);
    hipLaunchKernelGGL(k_rowsq, dim3(NE / 256), dim3(256), 0, stream, emb, esq, sums);
    hipLaunchKernelGGL(k_argmin, dim3(NZ / BM, NSPLIT), dim3(256), 0, stream,
                       z, emb, zsq, esq, ps1, pix);
    hipLaunchKernelGGL(k_merge, dim3(NZ / 256), dim3(256), 0, stream,
                       ps1, pix, idxb, out + (size_t)NZ * D);
    hipLaunchKernelGGL(k_gather, dim3(NZ / 4), dim3(256), 0, stream,
                       z, emb, idxb, out, sums);
    hipLaunchKernelGGL(k_pairwise, dim3(NE / BM, NSPLIT), dim3(256), 0, stream,
                       emb, esq, pmax, pmin);
    hipLaunchKernelGGL(k_mm_sum, dim3(NE / 256), dim3(256), 0, stream,
                       pmax, pmin, sums);
    hipLaunchKernelGGL(k_final, dim3(1), dim3(1), 0, stream, sums, out);
}

// Round 4
// 1332.979 us; speedup vs baseline: 1.2173x; 1.2173x over previous
//
#include <hip/hip_runtime.h>

#define D 256
#define NE 8192
#define NZ 16384
#define BM 128
#define BN 128
#define BK 32
#define LDA (BM + 4)            // padded k-major stride (floats)
#define NSPLIT_A 8              // argmin column splits -> 1024 blocks
#define SPLIT_NA (NE / NSPLIT_A)
#define NB (NE / BM)            // 64 block-rows for pairwise
#define NTRI (NB * (NB + 1) / 2)

// LDS swizzle: rotate row coord by 8*(skq&3) per k-quad group; 2-way banks on store.
// Pure permutation of storage location -> values & dot chain bit-identical.
#define SROT(kk) (8 * ((((kk) >> 2)) & 3))
#define SWZR(kk, r) ((((r) + SROT(kk)) & 127))

// workspace layout (bytes)
#define WS_SUMS   0                           // double[4]: 0=sum_emb2 1=sum_diff2 2=sum_maxmin
#define WS_ZSQ    64                          // float[NZ]
#define WS_ESQ    (WS_ZSQ + NZ * 4)           // float[NE]
#define WS_IDX    (WS_ESQ + NE * 4)           // int[NZ]
#define WS_PS1    (WS_IDX + NZ * 4)           // float[NZ*NSPLIT_A]
#define WS_PIX    (WS_PS1 + NZ * NSPLIT_A * 4)// int[NZ*NSPLIT_A]
#define WS_RMX    (WS_PIX + NZ * NSPLIT_A * 4)// unsigned[NE] row max (float bits)
#define WS_RMN    (WS_RMX + NE * 4)           // unsigned[NE] row min (float bits)

__device__ __forceinline__ float waveReduceSumF(float v) {
    v += __shfl_down(v, 32);
    v += __shfl_down(v, 16);
    v += __shfl_down(v, 8);
    v += __shfl_down(v, 4);
    v += __shfl_down(v, 2);
    v += __shfl_down(v, 1);
    return v;
}

__device__ __forceinline__ double waveReduceSumD(double v) {
    v += __shfl_down(v, 32);
    v += __shfl_down(v, 16);
    v += __shfl_down(v, 8);
    v += __shfl_down(v, 4);
    v += __shfl_down(v, 2);
    v += __shfl_down(v, 1);
    return v;
}

__global__ void k_init(double* sums) {
    sums[0] = 0.0; sums[1] = 0.0; sums[2] = 0.0; sums[3] = 0.0;
}

__global__ __launch_bounds__(256) void k_initmm(unsigned* __restrict__ rmx,
                                                unsigned* __restrict__ rmn) {
    const int n = blockIdx.x * 256 + threadIdx.x;
    rmx[n] = 0u;           // 0.0f
    rmn[n] = 0x7F800000u;  // +inf
}

// np.sum(x*x, axis=1) bit-exact (numpy pairwise summation, n=256)
__global__ __launch_bounds__(256) void k_rowsq(const float* __restrict__ src,
                                               float* __restrict__ rsq,
                                               double* __restrict__ sums) {
    const int row = blockIdx.x * 256 + threadIdx.x;
    const float* p = src + (size_t)row * D;
    float h[2];
#pragma unroll
    for (int half = 0; half < 2; ++half) {
        const float* q = p + half * 128;
        float4 a0 = *(const float4*)&q[0];
        float4 a1 = *(const float4*)&q[4];
        float r0 = __fmul_rn(a0.x, a0.x);
        float r1 = __fmul_rn(a0.y, a0.y);
        float r2 = __fmul_rn(a0.z, a0.z);
        float r3 = __fmul_rn(a0.w, a0.w);
        float r4 = __fmul_rn(a1.x, a1.x);
        float r5 = __fmul_rn(a1.y, a1.y);
        float r6 = __fmul_rn(a1.z, a1.z);
        float r7 = __fmul_rn(a1.w, a1.w);
#pragma unroll
        for (int i = 8; i < 128; i += 8) {
            const float4 b0 = *(const float4*)&q[i];
            const float4 b1 = *(const float4*)&q[i + 4];
            r0 = __fadd_rn(r0, __fmul_rn(b0.x, b0.x));
            r1 = __fadd_rn(r1, __fmul_rn(b0.y, b0.y));
            r2 = __fadd_rn(r2, __fmul_rn(b0.z, b0.z));
            r3 = __fadd_rn(r3, __fmul_rn(b0.w, b0.w));
            r4 = __fadd_rn(r4, __fmul_rn(b1.x, b1.x));
            r5 = __fadd_rn(r5, __fmul_rn(b1.y, b1.y));
            r6 = __fadd_rn(r6, __fmul_rn(b1.z, b1.z));
            r7 = __fadd_rn(r7, __fmul_rn(b1.w, b1.w));
        }
        const float t01 = __fadd_rn(r0, r1);
        const float t23 = __fadd_rn(r2, r3);
        const float t45 = __fadd_rn(r4, r5);
        const float t67 = __fadd_rn(r6, r7);
        h[half] = __fadd_rn(__fadd_rn(t01, t23), __fadd_rn(t45, t67));
    }
    const float tot = __fadd_rn(h[0], h[1]);
    rsq[row] = tot;
    if (sums != nullptr) {
        double s = waveReduceSumD((double)tot);
        if ((threadIdx.x & 63) == 0) atomicAdd(&sums[0], s);
    }
}

// ---- argmin over codes, np-fp32-exact: d = fl(fl(zsq+esq) - 2*dot_serial32) ----
__global__ __launch_bounds__(256) void k_argmin(const float* __restrict__ z,
                                                const float* __restrict__ emb,
                                                const float* __restrict__ zsq,
                                                const float* __restrict__ esq,
                                                float* __restrict__ ps1,
                                                int* __restrict__ pidx) {
    __shared__ float As[BK * LDA];
    __shared__ float Bs[BK * LDA];
    __shared__ float Sq[BN];

    const int t = threadIdx.x;
    const int row0  = blockIdx.x * BM;
    const int sp    = blockIdx.y;
    const int cbase = sp * SPLIT_NA;

    const int tr = t >> 4;
    const int tc = t & 15;
    const int sr  = t >> 3;
    const int skq = t & 7;
    const int wrot = 8 * (skq & 3);          // write-side rotation (same for c=0..3)

    float zqr[8];
#pragma unroll
    for (int i = 0; i < 8; ++i) zqr[i] = zsq[row0 + tr * 8 + i];

    float best[8];
    int   bidx[8];
#pragma unroll
    for (int i = 0; i < 8; ++i) { best[i] = 3.4e38f; bidx[i] = 0; }

    for (int ch = 0; ch < SPLIT_NA; ch += BN) {
        const int c0 = cbase + ch;
        if (t < BN) Sq[t] = esq[c0 + t];

        float acc[8][8];
#pragma unroll
        for (int i = 0; i < 8; ++i)
#pragma unroll
            for (int j = 0; j < 8; ++j) acc[i][j] = 0.f;

        for (int kb = 0; kb < D; kb += BK) {
            __syncthreads();
#pragma unroll
            for (int q = 0; q < 4; ++q) {
                const int r = sr + 32 * q;
                const int rr = (r + wrot) & 127;
                const float4 av = *(const float4*)&z[(size_t)(row0 + r) * D + kb + 4 * skq];
                const float4 bv = *(const float4*)&emb[(size_t)(c0 + r) * D + kb + 4 * skq];
                As[(4 * skq + 0) * LDA + rr] = av.x;
                As[(4 * skq + 1) * LDA + rr] = av.y;
                As[(4 * skq + 2) * LDA + rr] = av.z;
                As[(4 * skq + 3) * LDA + rr] = av.w;
                Bs[(4 * skq + 0) * LDA + rr] = bv.x;
                Bs[(4 * skq + 1) * LDA + rr] = bv.y;
                Bs[(4 * skq + 2) * LDA + rr] = bv.z;
                Bs[(4 * skq + 3) * LDA + rr] = bv.w;
            }
            __syncthreads();
#pragma unroll
            for (int k = 0; k < BK; ++k) {
                const float4 a0 = *(const float4*)&As[k * LDA + SWZR(k, tr * 8)];
                const float4 a1 = *(const float4*)&As[k * LDA + SWZR(k, tr * 8 + 4)];
                const float4 b0 = *(const float4*)&Bs[k * LDA + SWZR(k, tc * 4)];
                const float4 b1 = *(const float4*)&Bs[k * LDA + SWZR(k, 64 + tc * 4)];
                const float a[8] = {a0.x, a0.y, a0.z, a0.w, a1.x, a1.y, a1.z, a1.w};
                const float b[8] = {b0.x, b0.y, b0.z, b0.w, b1.x, b1.y, b1.z, b1.w};
#pragma unroll
                for (int i = 0; i < 8; ++i)
#pragma unroll
                    for (int j = 0; j < 8; ++j)
                        acc[i][j] = fmaf(a[i], b[j], acc[i][j]);
            }
        }
#pragma unroll
        for (int jj = 0; jj < 8; ++jj) {
            const int cloc = (jj < 4) ? (tc * 4 + jj) : (64 + tc * 4 + (jj - 4));
            const float sq = Sq[cloc];
            const int gcol = c0 + cloc;
#pragma unroll
            for (int i = 0; i < 8; ++i) {
                const float t1 = __fadd_rn(zqr[i], sq);
                const float s  = fmaf(-2.f, acc[i][jj], t1);
                if (s < best[i]) { best[i] = s; bidx[i] = gcol; }
            }
        }
        __syncthreads();
    }

    float* Rs = As;
    int*   Ri = (int*)Bs;
#pragma unroll
    for (int i = 0; i < 8; ++i) {
        Rs[(tr * 8 + i) * 16 + tc] = best[i];
        Ri[(tr * 8 + i) * 16 + tc] = bidx[i];
    }
    __syncthreads();
    if (t < BM) {
        float bs = Rs[t * 16];
        int   bi = Ri[t * 16];
#pragma unroll
        for (int c = 1; c < 16; ++c) {
            const float s = Rs[t * 16 + c];
            const int  ii = Ri[t * 16 + c];
            if (s < bs || (s == bs && ii < bi)) { bs = s; bi = ii; }
        }
        ps1[(size_t)(row0 + t) * NSPLIT_A + sp] = bs;
        pidx[(size_t)(row0 + t) * NSPLIT_A + sp] = bi;
    }
}

__global__ __launch_bounds__(256) void k_merge(const float* __restrict__ ps,
                                               const int* __restrict__ pi,
                                               int* __restrict__ idxbuf,
                                               float* __restrict__ outidx) {
    const int n = blockIdx.x * 256 + threadIdx.x;
    float bs = ps[n * NSPLIT_A];
    int   bi = pi[n * NSPLIT_A];
#pragma unroll
    for (int s2 = 1; s2 < NSPLIT_A; ++s2) {
        const float v = ps[n * NSPLIT_A + s2];
        const int  ii = pi[n * NSPLIT_A + s2];
        if (v < bs || (v == bs && ii < bi)) { bs = v; bi = ii; }
    }
    idxbuf[n] = bi;
    outidx[n] = (float)bi;
}

__global__ __launch_bounds__(256) void k_gather(const float* __restrict__ z,
                                                const float* __restrict__ emb,
                                                const int* __restrict__ idxbuf,
                                                float* __restrict__ out,
                                                double* __restrict__ sums) {
    const int row  = blockIdx.x * 4 + (threadIdx.x >> 6);
    const int lane = threadIdx.x & 63;
    const int idx  = idxbuf[row];
    const float4 e4 = *(const float4*)&emb[(size_t)idx * D + lane * 4];
    const float4 z4 = *(const float4*)&z[(size_t)row * D + lane * 4];
    *(float4*)&out[(size_t)row * D + lane * 4] = e4;
    const float dx = e4.x - z4.x, dy = e4.y - z4.y;
    const float dzv = e4.z - z4.z, dw = e4.w - z4.w;
    float s = dx * dx + dy * dy + dzv * dzv + dw * dw;
    s = waveReduceSumF(s);
    if (lane == 0) atomicAdd(&sums[1], (double)s);
}

// ---- pairwise cdist row max/min, upper-triangular tiles only (symmetric) ----
// each tile (bi,bj) updates row-stats for rows bi*BM.. and col-stats for cols bj*BM..
// via integer atomic max/min (valid: dd >= 0 -> float bits monotonic)
__global__ __launch_bounds__(256) void k_pairwise_sym(const float* __restrict__ emb,
                                                      const float* __restrict__ esq,
                                                      unsigned* __restrict__ rmxg,
                                                      unsigned* __restrict__ rmng) {
    __shared__ float As[BK * LDA];
    __shared__ float Bs[BK * LDA];
    __shared__ float Sq[BN];

    // linear -> upper-triangular (bi <= bj)
    int p = blockIdx.x;
    int bi = 0;
    while (p >= NB - bi) { p -= NB - bi; ++bi; }
    const int bj = bi + p;
    const int row0 = bi * BM;
    const int c0   = bj * BM;

    const int t = threadIdx.x;
    const int tr = t >> 4;
    const int tc = t & 15;
    const int sr  = t >> 3;
    const int skq = t & 7;
    const int wrot = 8 * (skq & 3);

    float rsq[8];
#pragma unroll
    for (int i = 0; i < 8; ++i) rsq[i] = esq[row0 + tr * 8 + i];
    if (t < BN) Sq[t] = esq[c0 + t];

    float acc[8][8];
#pragma unroll
    for (int i = 0; i < 8; ++i)
#pragma unroll
        for (int j = 0; j < 8; ++j) acc[i][j] = 0.f;

    for (int kb = 0; kb < D; kb += BK) {
        __syncthreads();
#pragma unroll
        for (int q = 0; q < 4; ++q) {
            const int r = sr + 32 * q;
            const int rr = (r + wrot) & 127;
            const float4 av = *(const float4*)&emb[(size_t)(row0 + r) * D + kb + 4 * skq];
            const float4 bv = *(const float4*)&emb[(size_t)(c0 + r) * D + kb + 4 * skq];
            As[(4 * skq + 0) * LDA + rr] = av.x;
            As[(4 * skq + 1) * LDA + rr] = av.y;
            As[(4 * skq + 2) * LDA + rr] = av.z;
            As[(4 * skq + 3) * LDA + rr] = av.w;
            Bs[(4 * skq + 0) * LDA + rr] = bv.x;
            Bs[(4 * skq + 1) * LDA + rr] = bv.y;
            Bs[(4 * skq + 2) * LDA + rr] = bv.z;
            Bs[(4 * skq + 3) * LDA + rr] = bv.w;
        }
        __syncthreads();
#pragma unroll
        for (int k = 0; k < BK; ++k) {
            const float4 a0 = *(const float4*)&As[k * LDA + SWZR(k, tr * 8)];
            const float4 a1 = *(const float4*)&As[k * LDA + SWZR(k, tr * 8 + 4)];
            const float4 b0 = *(const float4*)&Bs[k * LDA + SWZR(k, tc * 4)];
            const float4 b1 = *(const float4*)&Bs[k * LDA + SWZR(k, 64 + tc * 4)];
            const float a[8] = {a0.x, a0.y, a0.z, a0.w, a1.x, a1.y, a1.z, a1.w};
            const float b[8] = {b0.x, b0.y, b0.z, b0.w, b1.x, b1.y, b1.z, b1.w};
#pragma unroll
            for (int i = 0; i < 8; ++i)
#pragma unroll
                for (int j = 0; j < 8; ++j)
                    acc[i][j] = fmaf(a[i], b[j], acc[i][j]);
        }
    }

    float rmax[8], rmin[8], cmax[8], cmin[8];
#pragma unroll
    for (int i = 0; i < 8; ++i) { rmax[i] = 0.f; rmin[i] = 3.4e38f; cmax[i] = 0.f; cmin[i] = 3.4e38f; }

#pragma unroll
    for (int jj = 0; jj < 8; ++jj) {
        const int cloc = (jj < 4) ? (tc * 4 + jj) : (64 + tc * 4 + (jj - 4));
        const float sq = Sq[cloc];
#pragma unroll
        for (int i = 0; i < 8; ++i) {
            const float t1 = __fadd_rn(rsq[i], sq);
            const float d2 = fmaf(-2.f, acc[i][jj], t1);
            const float dd = (d2 > 0.f) ? sqrtf(d2) : 0.f;
            rmax[i] = fmaxf(rmax[i], dd);
            rmin[i] = fminf(rmin[i], dd);
            cmax[jj] = fmaxf(cmax[jj], dd);
            cmin[jj] = fminf(cmin[jj], dd);
        }
    }
    __syncthreads();

    // row stats: 16 threads (tc) share rows tr*8..+7
    float* Rmx = As;
    float* Rmn = Bs;
#pragma unroll
    for (int i = 0; i < 8; ++i) {
        Rmx[(tr * 8 + i) * 16 + tc] = rmax[i];
        Rmn[(tr * 8 + i) * 16 + tc] = rmin[i];
    }
    __syncthreads();
    if (t < BM) {
        float mx = Rmx[t * 16];
        float mn = Rmn[t * 16];
#pragma unroll
        for (int c = 1; c < 16; ++c) {
            mx = fmaxf(mx, Rmx[t * 16 + c]);
            mn = fminf(mn, Rmn[t * 16 + c]);
        }
        atomicMax(&rmxg[row0 + t], __float_as_uint(mx));
        atomicMin(&rmng[row0 + t], __float_as_uint(mn));
    }
    __syncthreads();

    // col stats: 16 threads (tr) share each col
#pragma unroll
    for (int jj = 0; jj < 8; ++jj) {
        const int cloc = (jj < 4) ? (tc * 4 + jj) : (64 + tc * 4 + (jj - 4));
        Rmx[cloc * 16 + tr] = cmax[jj];
        Rmn[cloc * 16 + tr] = cmin[jj];
    }
    __syncthreads();
    if (t < BM) {
        float mx = Rmx[t * 16];
        float mn = Rmn[t * 16];
#pragma unroll
        for (int c = 1; c < 16; ++c) {
            mx = fmaxf(mx, Rmx[t * 16 + c]);
            mn = fminf(mn, Rmn[t * 16 + c]);
        }
        atomicMax(&rmxg[c0 + t], __float_as_uint(mx));
        atomicMin(&rmng[c0 + t], __float_as_uint(mn));
    }
}

__global__ __launch_bounds__(256) void k_mm_sum(const unsigned* __restrict__ rmxg,
                                                const unsigned* __restrict__ rmng,
                                                double* __restrict__ sums) {
    const int n = blockIdx.x * 256 + threadIdx.x;
    const float mx = __uint_as_float(rmxg[n]);
    const float mn = __uint_as_float(rmng[n]);
    float v = mx - mn;
    v = waveReduceSumF(v);
    __shared__ float part[4];
    if ((threadIdx.x & 63) == 0) part[threadIdx.x >> 6] = v;
    __syncthreads();
    if (threadIdx.x == 0)
        atomicAdd(&sums[2], (double)(part[0] + part[1] + part[2] + part[3]));
}

__global__ void k_final(const double* __restrict__ sums, float* __restrict__ out) {
    const double loss = 1.25 * (sums[1] / (double)((size_t)NZ * D));
    const double qq   = 0.1 * (sums[2] / (double)NE) + 0.1 * sums[0];
    out[(size_t)NZ * D + NZ]     = (float)loss;
    out[(size_t)NZ * D + NZ + 1] = (float)qq;
}

extern "C" void kernel_launch(void* const* d_in, const int* in_sizes, int n_in,
                              void* d_out, int out_size, void* d_ws, size_t ws_size,
                              hipStream_t stream) {
    const float* z   = (const float*)d_in[0];
    const float* emb = (const float*)d_in[1];
    float* out = (float*)d_out;
    char*  ws  = (char*)d_ws;

    double*   sums = (double*)(ws + WS_SUMS);
    float*    zsq  = (float*)(ws + WS_ZSQ);
    float*    esq  = (float*)(ws + WS_ESQ);
    int*      idxb = (int*)(ws + WS_IDX);
    float*    ps1  = (float*)(ws + WS_PS1);
    int*      pix  = (int*)(ws + WS_PIX);
    unsigned* rmx  = (unsigned*)(ws + WS_RMX);
    unsigned* rmn  = (unsigned*)(ws + WS_RMN);

    hipLaunchKernelGGL(k_init, dim3(1), dim3(1), 0, stream, sums);
    hipLaunchKernelGGL(k_initmm, dim3(NE / 256), dim3(256), 0, stream, rmx, rmn);
    hipLaunchKernelGGL(k_rowsq, dim3(NZ / 256), dim3(256), 0, stream, z, zsq, (double*)nullptr);
    hipLaunchKernelGGL(k_rowsq, dim3(NE / 256), dim3(256), 0, stream, emb, esq, sums);
    hipLaunchKernelGGL(k_argmin, dim3(NZ / BM, NSPLIT_A), dim3(256), 0, stream,
                       z, emb, zsq, esq, ps1, pix);
    hipLaunchKernelGGL(k_merge, dim3(NZ / 256), dim3(256), 0, stream,
                       ps1, pix, idxb, out + (size_t)NZ * D);
    hipLaunchKernelGGL(k_gather, dim3(NZ / 4), dim3(256), 0, stream,
                       z, emb, idxb, out, sums);
    hipLaunchKernelGGL(k_pairwise_sym, dim3(NTRI), dim3(256), 0, stream,
                       emb, esq, rmx, rmn);
    hipLaunchKernelGGL(k_mm_sum, dim3(NE / 256), dim3(256), 0, stream,
                       rmx, rmn, sums);
    hipLaunchKernelGGL(k_final, dim3(1), dim3(1), 0, stream, sums, out);
}

// Round 5
// 872.960 us; speedup vs baseline: 1.8588x; 1.5270x over previous
//
#include <hip/hip_runtime.h>

#define D 256
#define NE 8192
#define NZ 16384
#define BM 128
#define BN 128
#define BK 32
#define LDA (BM + 4)
#define NB (NE / BM)
#define NTRI (NB * (NB + 1) / 2)
#define NSPLIT_A 8
#define SPLIT_NA (NE / NSPLIT_A)   // 1024
#define FSPLITS 32                 // fixup col splits (256 cols each)
#define GAPTH 6.0e-5f
#define LDH 40                     // fp16 LDS row stride (32 data + 8 pad)

// fp32-path LDS swizzle (round-4, kept for k_fix)
#define SROT(kk) (8 * ((((kk) >> 2)) & 3))
#define SWZR(kk, r) ((((r) + SROT(kk)) & 127))

typedef _Float16 f16x8 __attribute__((ext_vector_type(8)));
typedef _Float16 f16x4 __attribute__((ext_vector_type(4)));
typedef float f32x4 __attribute__((ext_vector_type(4)));

#define MFMA16(a, b, c) __builtin_amdgcn_mfma_f32_16x16x32_f16(a, b, c, 0, 0, 0)

// ---------------- workspace layout (bytes) ----------------
#define WS_SUMS   0                            // double[4]
#define WS_CNT    64                           // int
#define WS_ZSQ    256                          // float[NZ]
#define WS_ESQ    (WS_ZSQ + NZ * 4)            // float[NE]
#define WS_IDX    (WS_ESQ + NE * 4)            // int[NZ]
#define WS_PS1    (WS_IDX + NZ * 4)            // float[NZ*8]
#define WS_PS2    (WS_PS1 + NZ * NSPLIT_A * 4)
#define WS_PIX    (WS_PS2 + NZ * NSPLIT_A * 4)
#define WS_FLAGS  (WS_PIX + NZ * NSPLIT_A * 4) // int[NZ]
#define WS_RMX    (WS_FLAGS + NZ * 4)          // uint[NE]
#define WS_RMN    (WS_RMX + NE * 4)            // uint[NE]
#define WS_ZH     (WS_RMN + NE * 4)            // f16[NZ*D]  (aliased by FIXS/FIXI later)
#define WS_ZL     (WS_ZH + NZ * D * 2)         // f16[NZ*D]
#define WS_EH     (WS_ZL + NZ * D * 2)         // f16[NE*D]
#define WS_EL     (WS_EH + NE * D * 2)         // f16[NE*D]
// fix partials alias the ZH/ZL region (dead by fix time; fix reads z fp32)
#define WS_FIXS   WS_ZH                        // float[NZ*FSPLITS] (2 MB)
#define WS_FIXI   WS_ZL                        // int[NZ*FSPLITS]

__device__ __forceinline__ float waveReduceSumF(float v) {
    v += __shfl_down(v, 32); v += __shfl_down(v, 16); v += __shfl_down(v, 8);
    v += __shfl_down(v, 4);  v += __shfl_down(v, 2);  v += __shfl_down(v, 1);
    return v;
}
__device__ __forceinline__ double waveReduceSumD(double v) {
    v += __shfl_down(v, 32); v += __shfl_down(v, 16); v += __shfl_down(v, 8);
    v += __shfl_down(v, 4);  v += __shfl_down(v, 2);  v += __shfl_down(v, 1);
    return v;
}

__global__ void k_init(double* sums, int* cnt) {
    sums[0] = 0.0; sums[1] = 0.0; sums[2] = 0.0; sums[3] = 0.0;
    *cnt = 0;
}

__global__ __launch_bounds__(256) void k_initmm(unsigned* __restrict__ rmx,
                                                unsigned* __restrict__ rmn) {
    const int n = blockIdx.x * 256 + threadIdx.x;
    rmx[n] = 0u;
    rmn[n] = 0x7F800000u;
}

// np.sum(x*x, axis=1) bit-exact (numpy pairwise summation, n=256)
__global__ __launch_bounds__(256) void k_rowsq(const float* __restrict__ src,
                                               float* __restrict__ rsq,
                                               double* __restrict__ sums) {
    const int row = blockIdx.x * 256 + threadIdx.x;
    const float* p = src + (size_t)row * D;
    float h[2];
#pragma unroll
    for (int half = 0; half < 2; ++half) {
        const float* q = p + half * 128;
        float4 a0 = *(const float4*)&q[0];
        float4 a1 = *(const float4*)&q[4];
        float r0 = __fmul_rn(a0.x, a0.x);
        float r1 = __fmul_rn(a0.y, a0.y);
        float r2 = __fmul_rn(a0.z, a0.z);
        float r3 = __fmul_rn(a0.w, a0.w);
        float r4 = __fmul_rn(a1.x, a1.x);
        float r5 = __fmul_rn(a1.y, a1.y);
        float r6 = __fmul_rn(a1.z, a1.z);
        float r7 = __fmul_rn(a1.w, a1.w);
#pragma unroll
        for (int i = 8; i < 128; i += 8) {
            const float4 b0 = *(const float4*)&q[i];
            const float4 b1 = *(const float4*)&q[i + 4];
            r0 = __fadd_rn(r0, __fmul_rn(b0.x, b0.x));
            r1 = __fadd_rn(r1, __fmul_rn(b0.y, b0.y));
            r2 = __fadd_rn(r2, __fmul_rn(b0.z, b0.z));
            r3 = __fadd_rn(r3, __fmul_rn(b0.w, b0.w));
            r4 = __fadd_rn(r4, __fmul_rn(b1.x, b1.x));
            r5 = __fadd_rn(r5, __fmul_rn(b1.y, b1.y));
            r6 = __fadd_rn(r6, __fmul_rn(b1.z, b1.z));
            r7 = __fadd_rn(r7, __fmul_rn(b1.w, b1.w));
        }
        const float t01 = __fadd_rn(r0, r1);
        const float t23 = __fadd_rn(r2, r3);
        const float t45 = __fadd_rn(r4, r5);
        const float t67 = __fadd_rn(r6, r7);
        h[half] = __fadd_rn(__fadd_rn(t01, t23), __fadd_rn(t45, t67));
    }
    const float tot = __fadd_rn(h[0], h[1]);
    rsq[row] = tot;
    if (sums != nullptr) {
        double s = waveReduceSumD((double)tot);
        if ((threadIdx.x & 63) == 0) atomicAdd(&sums[0], s);
    }
}

// z -> zh + zl*2^-11 (fp16 split)
__global__ __launch_bounds__(256) void k_cvt_z(const float* __restrict__ z,
                                               _Float16* __restrict__ zh,
                                               _Float16* __restrict__ zl) {
    const size_t g = (size_t)blockIdx.x * 256 + threadIdx.x;
    const float4 x = *(const float4*)&z[g * 4];
    f16x4 hv, lv;
    float xs[4] = {x.x, x.y, x.z, x.w};
#pragma unroll
    for (int i = 0; i < 4; ++i) {
        const _Float16 hh = (_Float16)xs[i];
        const float r = xs[i] - (float)hh;            // exact
        hv[i] = hh;
        lv[i] = (_Float16)(r * 2048.0f);              // *2^11
    }
    *(f16x4*)&zh[g * 4] = hv;
    *(f16x4*)&zl[g * 4] = lv;
}

// e -> eh*2^-13 + el*2^-24 (fp16 split, scaled to normal range)
__global__ __launch_bounds__(256) void k_cvt_e(const float* __restrict__ e,
                                               _Float16* __restrict__ eh,
                                               _Float16* __restrict__ el) {
    const size_t g = (size_t)blockIdx.x * 256 + threadIdx.x;
    const float4 x = *(const float4*)&e[g * 4];
    f16x4 hv, lv;
    float xs[4] = {x.x, x.y, x.z, x.w};
#pragma unroll
    for (int i = 0; i < 4; ++i) {
        const _Float16 hh = (_Float16)(xs[i] * 8192.0f);      // *2^13
        const float r = xs[i] - (float)hh * (1.0f / 8192.0f); // exact
        hv[i] = hh;
        lv[i] = (_Float16)(r * 16777216.0f);                  // *2^24
    }
    *(f16x4*)&eh[g * 4] = hv;
    *(f16x4*)&el[g * 4] = lv;
}

// ---- MFMA argmin pass: accurate scores + per-row top-2 per split ----
// block: 128 rows x (split of 1024 cols in 16 chunks of 64); 4 waves x 32 rows
__global__ __launch_bounds__(256) void k_argmin_mfma(
        const _Float16* __restrict__ zh, const _Float16* __restrict__ zl,
        const _Float16* __restrict__ eh, const _Float16* __restrict__ el,
        const float* __restrict__ zsq, const float* __restrict__ esq,
        float* __restrict__ ps1, float* __restrict__ ps2, int* __restrict__ pix) {
    __shared__ __align__(16) char smem[30720];
    _Float16* Ah = (_Float16*)smem;            // [128][LDH]
    _Float16* Al = (_Float16*)(smem + 10240);  // [128][LDH]
    _Float16* Bh = (_Float16*)(smem + 20480);  // [64][LDH]
    _Float16* Bl = (_Float16*)(smem + 25600);  // [64][LDH]

    const int t = threadIdx.x;
    const int lane = t & 63;
    const int w = t >> 6;
    const int quad = lane >> 4;
    const int l15 = lane & 15;
    const int row0 = blockIdx.x * BM;
    const int sp = blockIdx.y;
    const int cb = sp * SPLIT_NA;
    const int wrow = row0 + w * 32;

    float zq[8];
#pragma unroll
    for (int mi = 0; mi < 2; ++mi)
#pragma unroll
        for (int r = 0; r < 4; ++r)
            zq[mi * 4 + r] = zsq[wrow + mi * 16 + quad * 4 + r];

    float b1[8], b2[8];
    int i1[8];
#pragma unroll
    for (int s = 0; s < 8; ++s) { b1[s] = 3.4e38f; b2[s] = 3.4e38f; i1[s] = 0; }

    const int ar = t >> 1;          // A staging row (pairs of threads)
    const int aseg = t & 1;         // two 8-elt segs per half-row pair? (see below)
    const int br = t >> 2;          // B staging row for 64-row tile
    const int bseg = t & 3;

    for (int ch = 0; ch < 16; ++ch) {
        const int c0 = cb + ch * 64;

        f32x4 acc13[2][4], acc24[2][4];
#pragma unroll
        for (int mi = 0; mi < 2; ++mi)
#pragma unroll
            for (int nj = 0; nj < 4; ++nj) {
                acc13[mi][nj] = (f32x4){0.f, 0.f, 0.f, 0.f};
                acc24[mi][nj] = (f32x4){0.f, 0.f, 0.f, 0.f};
            }

        for (int kb = 0; kb < D; kb += BK) {
            __syncthreads();
            // A tiles: 128 rows x 32 fp16 = 512 units of 8 fp16; thread does u=t, u=t+256
#pragma unroll
            for (int uu = 0; uu < 2; ++uu) {
                const int u = t + uu * 256;
                const int r = u >> 2, seg = u & 3;
                *(uint4*)&Ah[r * LDH + seg * 8] =
                    *(const uint4*)&zh[(size_t)(row0 + r) * D + kb + seg * 8];
                *(uint4*)&Al[r * LDH + seg * 8] =
                    *(const uint4*)&zl[(size_t)(row0 + r) * D + kb + seg * 8];
            }
            // B tiles: 64 rows x 32 = 256 units; one each for Bh, Bl
            {
                const int r = br, seg = bseg;
                *(uint4*)&Bh[r * LDH + seg * 8] =
                    *(const uint4*)&eh[(size_t)(c0 + r) * D + kb + seg * 8];
                *(uint4*)&Bl[r * LDH + seg * 8] =
                    *(const uint4*)&el[(size_t)(c0 + r) * D + kb + seg * 8];
            }
            __syncthreads();

            f16x8 ah[2], al[2], bh[4], bl[4];
#pragma unroll
            for (int mi = 0; mi < 2; ++mi) {
                const int rowa = (w * 32 + mi * 16 + l15) * LDH + quad * 8;
                ah[mi] = *(const f16x8*)&Ah[rowa];
                al[mi] = *(const f16x8*)&Al[rowa];
            }
#pragma unroll
            for (int nj = 0; nj < 4; ++nj) {
                const int rowb = (nj * 16 + l15) * LDH + quad * 8;
                bh[nj] = *(const f16x8*)&Bh[rowb];
                bl[nj] = *(const f16x8*)&Bl[rowb];
            }
#pragma unroll
            for (int mi = 0; mi < 2; ++mi)
#pragma unroll
                for (int nj = 0; nj < 4; ++nj) {
                    acc13[mi][nj] = MFMA16(ah[mi], bh[nj], acc13[mi][nj]);
                    acc24[mi][nj] = MFMA16(al[mi], bh[nj], acc24[mi][nj]);
                    acc24[mi][nj] = MFMA16(ah[mi], bl[nj], acc24[mi][nj]);
                }
        }

        // epilogue: accurate score x~ = (fl(zsq+esq)-zsq) - 2*dot ; top-2 per row slot
#pragma unroll
        for (int nj = 0; nj < 4; ++nj) {
            const int gcol = c0 + nj * 16 + l15;
            const float eqv = esq[gcol];
#pragma unroll
            for (int mi = 0; mi < 2; ++mi)
#pragma unroll
                for (int r = 0; r < 4; ++r) {
                    const int s = mi * 4 + r;
                    const float dot = acc13[mi][nj][r] * 0x1p-13f
                                    + acc24[mi][nj][r] * 0x1p-24f;
                    const float t1 = __fadd_rn(zq[s], eqv);
                    const float v = __fsub_rn(t1, zq[s]);  // exact (Sterbenz)
                    const float sc = fmaf(-2.f, dot, v);
                    if (sc < b1[s]) { b2[s] = b1[s]; b1[s] = sc; i1[s] = gcol; }
                    else if (sc < b2[s]) b2[s] = sc;
                }
        }
    }

    // per-row merge across the 16 lane-columns (LDS reuse)
    __syncthreads();
    float* MB1 = (float*)smem;            // [128][16]
    float* MB2 = (float*)(smem + 8192);
    int*   MI  = (int*)(smem + 16384);
#pragma unroll
    for (int s = 0; s < 8; ++s) {
        const int rl = w * 32 + (s >> 2) * 16 + quad * 4 + (s & 3);
        MB1[rl * 16 + l15] = b1[s];
        MB2[rl * 16 + l15] = b2[s];
        MI[rl * 16 + l15] = i1[s];
    }
    __syncthreads();
    if (t < BM) {
        float v1 = MB1[t * 16], v2 = MB2[t * 16];
        int ii1 = MI[t * 16];
#pragma unroll
        for (int c = 1; c < 16; ++c) {
            const float s1 = MB1[t * 16 + c];
            const float s2 = MB2[t * 16 + c];
            const int ii = MI[t * 16 + c];
            if (s1 < v1 || (s1 == v1 && ii < ii1)) {
                v2 = fminf(fminf(v2, v1), s2);
                v1 = s1; ii1 = ii;
            } else {
                v2 = fminf(v2, s1);
            }
        }
        ps1[(size_t)(row0 + t) * NSPLIT_A + sp] = v1;
        ps2[(size_t)(row0 + t) * NSPLIT_A + sp] = v2;
        pix[(size_t)(row0 + t) * NSPLIT_A + sp] = ii1;
    }
}

// merge splits; provisional idx for all; flag near-ties for np-exact repair
__global__ __launch_bounds__(256) void k_merge(const float* __restrict__ ps1,
                                               const float* __restrict__ ps2,
                                               const int* __restrict__ pi,
                                               int* __restrict__ idxbuf,
                                               float* __restrict__ outidx,
                                               int* __restrict__ cnt,
                                               int* __restrict__ flags) {
    const int n = blockIdx.x * 256 + threadIdx.x;
    float v1 = ps1[n * NSPLIT_A];
    float v2 = ps2[n * NSPLIT_A];
    int ii1 = pi[n * NSPLIT_A];
#pragma unroll
    for (int s = 1; s < NSPLIT_A; ++s) {
        const float s1 = ps1[n * NSPLIT_A + s];
        const float s2 = ps2[n * NSPLIT_A + s];
        const int ii = pi[n * NSPLIT_A + s];
        if (s1 < v1 || (s1 == v1 && ii < ii1)) {
            v2 = fminf(fminf(v2, v1), s2);
            v1 = s1; ii1 = ii;
        } else {
            v2 = fminf(v2, s1);
        }
    }
    idxbuf[n] = ii1;
    outidx[n] = (float)ii1;
    if (v2 - v1 < GAPTH) {
        const int p = atomicAdd(cnt, 1);
        flags[p] = n;
    }
}

// ---- np-bit-exact fp32 rescan of flagged rows (round-4 machinery, gathered rows) ----
__global__ __launch_bounds__(256) void k_fix(const float* __restrict__ z,
                                             const float* __restrict__ emb,
                                             const float* __restrict__ zsq,
                                             const float* __restrict__ esq,
                                             const int* __restrict__ cnt,
                                             const int* __restrict__ flags,
                                             float* __restrict__ fixs,
                                             int* __restrict__ fixi) {
    __shared__ float As[BK * LDA];
    __shared__ float Bs[BK * LDA];
    __shared__ float Sq[BN];
    __shared__ int frow[BM];

    const int t = threadIdx.x;
    const int tr = t >> 4;
    const int tc = t & 15;
    const int sr = t >> 3;
    const int skq = t & 7;
    const int wrot = 8 * (skq & 3);
    const int nflag = *cnt;
    const int c0base = blockIdx.y * (NE / FSPLITS);  // 256 cols per split

    for (int rb = blockIdx.x; rb * BM < nflag; rb += gridDim.x) {
        if (t < BM) {
            const int fi = rb * BM + t;
            frow[t] = (fi < nflag) ? flags[fi] : 0;
        }
        __syncthreads();

        float zqr[8];
#pragma unroll
        for (int i = 0; i < 8; ++i) zqr[i] = zsq[frow[tr * 8 + i]];

        float best[8];
        int bidx[8];
#pragma unroll
        for (int i = 0; i < 8; ++i) { best[i] = 3.4e38f; bidx[i] = 0; }

        for (int ch = 0; ch < 2; ++ch) {
            const int c0 = c0base + ch * BN;
            if (t < BN) Sq[t] = esq[c0 + t];

            float acc[8][8];
#pragma unroll
            for (int i = 0; i < 8; ++i)
#pragma unroll
                for (int j = 0; j < 8; ++j) acc[i][j] = 0.f;

            for (int kb = 0; kb < D; kb += BK) {
                __syncthreads();
#pragma unroll
                for (int q = 0; q < 4; ++q) {
                    const int r = sr + 32 * q;
                    const int rr = (r + wrot) & 127;
                    const float4 av = *(const float4*)&z[(size_t)frow[r] * D + kb + 4 * skq];
                    const float4 bv = *(const float4*)&emb[(size_t)(c0 + r) * D + kb + 4 * skq];
                    As[(4 * skq + 0) * LDA + rr] = av.x;
                    As[(4 * skq + 1) * LDA + rr] = av.y;
                    As[(4 * skq + 2) * LDA + rr] = av.z;
                    As[(4 * skq + 3) * LDA + rr] = av.w;
                    Bs[(4 * skq + 0) * LDA + rr] = bv.x;
                    Bs[(4 * skq + 1) * LDA + rr] = bv.y;
                    Bs[(4 * skq + 2) * LDA + rr] = bv.z;
                    Bs[(4 * skq + 3) * LDA + rr] = bv.w;
                }
                __syncthreads();
#pragma unroll
                for (int k = 0; k < BK; ++k) {
                    const float4 a0 = *(const float4*)&As[k * LDA + SWZR(k, tr * 8)];
                    const float4 a1 = *(const float4*)&As[k * LDA + SWZR(k, tr * 8 + 4)];
                    const float4 b0 = *(const float4*)&Bs[k * LDA + SWZR(k, tc * 4)];
                    const float4 b1 = *(const float4*)&Bs[k * LDA + SWZR(k, 64 + tc * 4)];
                    const float a[8] = {a0.x, a0.y, a0.z, a0.w, a1.x, a1.y, a1.z, a1.w};
                    const float b[8] = {b0.x, b0.y, b0.z, b0.w, b1.x, b1.y, b1.z, b1.w};
#pragma unroll
                    for (int i = 0; i < 8; ++i)
#pragma unroll
                        for (int j = 0; j < 8; ++j)
                            acc[i][j] = fmaf(a[i], b[j], acc[i][j]);
                }
            }
#pragma unroll
            for (int jj = 0; jj < 8; ++jj) {
                const int cloc = (jj < 4) ? (tc * 4 + jj) : (64 + tc * 4 + (jj - 4));
                const float sq = Sq[cloc];
                const int gcol = c0 + cloc;
#pragma unroll
                for (int i = 0; i < 8; ++i) {
                    const float t1 = __fadd_rn(zqr[i], sq);
                    const float s = fmaf(-2.f, acc[i][jj], t1);
                    if (s < best[i]) { best[i] = s; bidx[i] = gcol; }
                }
            }
            __syncthreads();
        }

        float* Rs = As;
        int* Ri = (int*)Bs;
#pragma unroll
        for (int i = 0; i < 8; ++i) {
            Rs[(tr * 8 + i) * 16 + tc] = best[i];
            Ri[(tr * 8 + i) * 16 + tc] = bidx[i];
        }
        __syncthreads();
        if (t < BM) {
            float bs = Rs[t * 16];
            int bi = Ri[t * 16];
#pragma unroll
            for (int c = 1; c < 16; ++c) {
                const float s = Rs[t * 16 + c];
                const int ii = Ri[t * 16 + c];
                if (s < bs || (s == bs && ii < bi)) { bs = s; bi = ii; }
            }
            const int fi = rb * BM + t;
            if (fi < nflag) {
                fixs[(size_t)fi * FSPLITS + blockIdx.y] = bs;
                fixi[(size_t)fi * FSPLITS + blockIdx.y] = bi;
            }
        }
        __syncthreads();
    }
}

__global__ __launch_bounds__(256) void k_fixmerge(const int* __restrict__ cnt,
                                                  const int* __restrict__ flags,
                                                  const float* __restrict__ fixs,
                                                  const int* __restrict__ fixi,
                                                  int* __restrict__ idxbuf,
                                                  float* __restrict__ outidx) {
    const int nflag = *cnt;
    for (int f = blockIdx.x * 256 + threadIdx.x; f < nflag; f += 16384) {
        float bs = fixs[(size_t)f * FSPLITS];
        int bi = fixi[(size_t)f * FSPLITS];
#pragma unroll 4
        for (int s = 1; s < FSPLITS; ++s) {
            const float v = fixs[(size_t)f * FSPLITS + s];
            const int ii = fixi[(size_t)f * FSPLITS + s];
            if (v < bs || (v == bs && ii < bi)) { bs = v; bi = ii; }
        }
        const int row = flags[f];
        idxbuf[row] = bi;
        outidx[row] = (float)bi;
    }
}

__global__ __launch_bounds__(256) void k_gather(const float* __restrict__ z,
                                                const float* __restrict__ emb,
                                                const int* __restrict__ idxbuf,
                                                float* __restrict__ out,
                                                double* __restrict__ sums) {
    const int row = blockIdx.x * 4 + (threadIdx.x >> 6);
    const int lane = threadIdx.x & 63;
    const int idx = idxbuf[row];
    const float4 e4 = *(const float4*)&emb[(size_t)idx * D + lane * 4];
    const float4 z4 = *(const float4*)&z[(size_t)row * D + lane * 4];
    *(float4*)&out[(size_t)row * D + lane * 4] = e4;
    const float dx = e4.x - z4.x, dy = e4.y - z4.y;
    const float dzv = e4.z - z4.z, dw = e4.w - z4.w;
    float s = dx * dx + dy * dy + dzv * dzv + dw * dw;
    s = waveReduceSumF(s);
    if (lane == 0) atomicAdd(&sums[1], (double)s);
}

// ---- pairwise cdist row min/max via fp16 MFMA, triangular tiles ----
__global__ __launch_bounds__(256) void k_pairwise_mfma(const _Float16* __restrict__ eh,
                                                       const float* __restrict__ esq,
                                                       unsigned* __restrict__ rmxg,
                                                       unsigned* __restrict__ rmng) {
    __shared__ __align__(16) char smem[20480];
    _Float16* Ah = (_Float16*)smem;            // [128][LDH]
    _Float16* Bh = (_Float16*)(smem + 10240);  // [128][LDH]

    int p = blockIdx.x;
    int bi = 0;
    while (p >= NB - bi) { p -= NB - bi; ++bi; }
    const int bj = bi + p;
    const int row0 = bi * BM;
    const int c0 = bj * BM;

    const int t = threadIdx.x;
    const int lane = t & 63;
    const int w = t >> 6;
    const int quad = lane >> 4;
    const int l15 = lane & 15;

    float esqR[8], esqC[8];
#pragma unroll
    for (int mi = 0; mi < 2; ++mi)
#pragma unroll
        for (int r = 0; r < 4; ++r)
            esqR[mi * 4 + r] = esq[row0 + w * 32 + mi * 16 + quad * 4 + r];
#pragma unroll
    for (int nj = 0; nj < 8; ++nj) esqC[nj] = esq[c0 + nj * 16 + l15];

    f32x4 acc[2][8];
#pragma unroll
    for (int mi = 0; mi < 2; ++mi)
#pragma unroll
        for (int nj = 0; nj < 8; ++nj) acc[mi][nj] = (f32x4){0.f, 0.f, 0.f, 0.f};

    for (int kb = 0; kb < D; kb += BK) {
        __syncthreads();
#pragma unroll
        for (int uu = 0; uu < 2; ++uu) {
            const int u = t + uu * 256;
            const int r = u >> 2, seg = u & 3;
            *(uint4*)&Ah[r * LDH + seg * 8] =
                *(const uint4*)&eh[(size_t)(row0 + r) * D + kb + seg * 8];
            *(uint4*)&Bh[r * LDH + seg * 8] =
                *(const uint4*)&eh[(size_t)(c0 + r) * D + kb + seg * 8];
        }
        __syncthreads();

        f16x8 ah[2], bh[8];
#pragma unroll
        for (int mi = 0; mi < 2; ++mi)
            ah[mi] = *(const f16x8*)&Ah[(w * 32 + mi * 16 + l15) * LDH + quad * 8];
#pragma unroll
        for (int nj = 0; nj < 8; ++nj)
            bh[nj] = *(const f16x8*)&Bh[(nj * 16 + l15) * LDH + quad * 8];
#pragma unroll
        for (int mi = 0; mi < 2; ++mi)
#pragma unroll
            for (int nj = 0; nj < 8; ++nj)
                acc[mi][nj] = MFMA16(ah[mi], bh[nj], acc[mi][nj]);
    }

    // d2 (clamped >= 0); min/max tracked on d2, sqrt applied at the end
    float rmn[8], rmx[8], cmn[8], cmx[8];
#pragma unroll
    for (int s = 0; s < 8; ++s) { rmn[s] = 3.4e38f; rmx[s] = 0.f; cmn[s] = 3.4e38f; cmx[s] = 0.f; }
#pragma unroll
    for (int mi = 0; mi < 2; ++mi)
#pragma unroll
        for (int nj = 0; nj < 8; ++nj)
#pragma unroll
            for (int r = 0; r < 4; ++r) {
                const int s = mi * 4 + r;
                const float t1 = __fadd_rn(esqR[s], esqC[nj]);
                const float d2 = fmaf(-0x1p-25f, acc[mi][nj][r], t1);  // dot scale 2^-26, x2
                const float d2c = fmaxf(d2, 0.f);
                rmn[s] = fminf(rmn[s], d2c);
                rmx[s] = fmaxf(rmx[s], d2c);
                cmn[nj] = fminf(cmn[nj], d2c);
                cmx[nj] = fmaxf(cmx[nj], d2c);
            }

    __syncthreads();
    float* Mx = (float*)smem;           // [128][16]
    float* Mn = (float*)(smem + 8192);
    // rows
#pragma unroll
    for (int s = 0; s < 8; ++s) {
        const int rl = w * 32 + (s >> 2) * 16 + quad * 4 + (s & 3);
        Mx[rl * 16 + l15] = rmx[s];
        Mn[rl * 16 + l15] = rmn[s];
    }
    __syncthreads();
    if (t < BM) {
        float mx = Mx[t * 16], mn = Mn[t * 16];
#pragma unroll
        for (int c = 1; c < 16; ++c) {
            mx = fmaxf(mx, Mx[t * 16 + c]);
            mn = fminf(mn, Mn[t * 16 + c]);
        }
        atomicMax(&rmxg[row0 + t], __float_as_uint(mx));
        atomicMin(&rmng[row0 + t], __float_as_uint(mn));
    }
    __syncthreads();
    // cols (symmetric contribution)
#pragma unroll
    for (int nj = 0; nj < 8; ++nj) {
        const int cl = nj * 16 + l15;
        Mx[cl * 16 + w * 4 + quad] = cmx[nj];
        Mn[cl * 16 + w * 4 + quad] = cmn[nj];
    }
    __syncthreads();
    if (t < BM) {
        float mx = Mx[t * 16], mn = Mn[t * 16];
#pragma unroll
        for (int c = 1; c < 16; ++c) {
            mx = fmaxf(mx, Mx[t * 16 + c]);
            mn = fminf(mn, Mn[t * 16 + c]);
        }
        atomicMax(&rmxg[c0 + t], __float_as_uint(mx));
        atomicMin(&rmng[c0 + t], __float_as_uint(mn));
    }
}

__global__ __launch_bounds__(256) void k_mm_sum(const unsigned* __restrict__ rmxg,
                                                const unsigned* __restrict__ rmng,
                                                double* __restrict__ sums) {
    const int n = blockIdx.x * 256 + threadIdx.x;
    const float mx = sqrtf(__uint_as_float(rmxg[n]));
    const float mn = sqrtf(__uint_as_float(rmng[n]));
    float v = mx - mn;
    v = waveReduceSumF(v);
    __shared__ float part[4];
    if ((threadIdx.x & 63) == 0) part[threadIdx.x >> 6] = v;
    __syncthreads();
    if (threadIdx.x == 0)
        atomicAdd(&sums[2], (double)(part[0] + part[1] + part[2] + part[3]));
}

__global__ void k_final(const double* __restrict__ sums, float* __restrict__ out) {
    const double loss = 1.25 * (sums[1] / (double)((size_t)NZ * D));
    const double qq = 0.1 * (sums[2] / (double)NE) + 0.1 * sums[0];
    out[(size_t)NZ * D + NZ] = (float)loss;
    out[(size_t)NZ * D + NZ + 1] = (float)qq;
}

extern "C" void kernel_launch(void* const* d_in, const int* in_sizes, int n_in,
                              void* d_out, int out_size, void* d_ws, size_t ws_size,
                              hipStream_t stream) {
    const float* z = (const float*)d_in[0];
    const float* emb = (const float*)d_in[1];
    float* out = (float*)d_out;
    char* ws = (char*)d_ws;

    double* sums = (double*)(ws + WS_SUMS);
    int* cnt = (int*)(ws + WS_CNT);
    float* zsq = (float*)(ws + WS_ZSQ);
    float* esq = (float*)(ws + WS_ESQ);
    int* idxb = (int*)(ws + WS_IDX);
    float* ps1 = (float*)(ws + WS_PS1);
    float* ps2 = (float*)(ws + WS_PS2);
    int* pix = (int*)(ws + WS_PIX);
    int* flags = (int*)(ws + WS_FLAGS);
    unsigned* rmx = (unsigned*)(ws + WS_RMX);
    unsigned* rmn = (unsigned*)(ws + WS_RMN);
    _Float16* zh = (_Float16*)(ws + WS_ZH);
    _Float16* zl = (_Float16*)(ws + WS_ZL);
    _Float16* eh = (_Float16*)(ws + WS_EH);
    _Float16* el = (_Float16*)(ws + WS_EL);
    float* fixs = (float*)(ws + WS_FIXS);
    int* fixi = (int*)(ws + WS_FIXI);

    hipLaunchKernelGGL(k_init, dim3(1), dim3(1), 0, stream, sums, cnt);
    hipLaunchKernelGGL(k_initmm, dim3(NE / 256), dim3(256), 0, stream, rmx, rmn);
    hipLaunchKernelGGL(k_rowsq, dim3(NZ / 256), dim3(256), 0, stream, z, zsq, (double*)nullptr);
    hipLaunchKernelGGL(k_rowsq, dim3(NE / 256), dim3(256), 0, stream, emb, esq, sums);
    hipLaunchKernelGGL(k_cvt_z, dim3(NZ * D / 4 / 256), dim3(256), 0, stream, z, zh, zl);
    hipLaunchKernelGGL(k_cvt_e, dim3(NE * D / 4 / 256), dim3(256), 0, stream, emb, eh, el);
    hipLaunchKernelGGL(k_argmin_mfma, dim3(NZ / BM, NSPLIT_A), dim3(256), 0, stream,
                       zh, zl, eh, el, zsq, esq, ps1, ps2, pix);
    hipLaunchKernelGGL(k_pairwise_mfma, dim3(NTRI), dim3(256), 0, stream,
                       eh, esq, rmx, rmn);
    hipLaunchKernelGGL(k_merge, dim3(NZ / 256), dim3(256), 0, stream,
                       ps1, ps2, pix, idxb, out + (size_t)NZ * D, cnt, flags);
    hipLaunchKernelGGL(k_fix, dim3(16, FSPLITS), dim3(256), 0, stream,
                       z, emb, zsq, esq, cnt, flags, fixs, fixi);
    hipLaunchKernelGGL(k_fixmerge, dim3(64), dim3(256), 0, stream,
                       cnt, flags, fixs, fixi, idxb, out + (size_t)NZ * D);
    hipLaunchKernelGGL(k_gather, dim3(NZ / 4), dim3(256), 0, stream,
                       z, emb, idxb, out, sums);
    hipLaunchKernelGGL(k_mm_sum, dim3(NE / 256), dim3(256), 0, stream,
                       rmx, rmn, sums);
    hipLaunchKernelGGL(k_final, dim3(1), dim3(1), 0, stream, sums, out);
}